// Round 13
// baseline (134.844 us; speedup 1.0000x reference)
//
#include <hip/hip_runtime.h>

typedef unsigned short u16;
typedef unsigned int u32;
typedef __attribute__((ext_vector_type(8))) short short8;
typedef __attribute__((ext_vector_type(4))) short s16x4;
typedef __attribute__((ext_vector_type(4))) float f32x4;
typedef __attribute__((ext_vector_type(16))) float f32x16;

#define DEVI __device__ __forceinline__

// B=2, L=S=2048, D=1024, H=16, E=64
#define LSEQ 2048
#define DMODEL 1024
#define NH 16
#define EHD 64

// scores scale folded into Q projection: 1/sqrt(64) * log2(e)
#define QSCALE 0.18033688011112042f

#if __has_builtin(__builtin_amdgcn_exp2f)
#define EXP2(x) __builtin_amdgcn_exp2f(x)
#else
#define EXP2(x) exp2f(x)
#endif

DEVI u16 f2b(float f) {
    u32 u = __float_as_uint(f);
    return (u16)((u + 0x7FFFu + ((u >> 16) & 1u)) >> 16);
}

DEVI u32 cvtpk(float lo, float hi) {
    u32 r;
    asm("v_cvt_pk_bf16_f32 %0, %1, %2" : "=v"(r) : "v"(lo), "v"(hi));
    return r;
}

DEVI void swap32(u32& a, u32& b) {
    asm("v_permlane32_swap_b32 %0, %1" : "+v"(a), "+v"(b));
}

DEVI short8 mk8(u32 a0, u32 a1, u32 a2, u32 a3) {
    union { u32 u[4]; short8 s; } x;
    x.u[0] = a0; x.u[1] = a1; x.u[2] = a2; x.u[3] = a3;
    return x.s;
}

DEVI void async_cp16(const void* g, void* l) {
    __builtin_amdgcn_global_load_lds((const __attribute__((address_space(1))) u32*)g,
                                     (__attribute__((address_space(3))) u32*)l, 16, 0, 0);
}

// read 16B from an XOR-swizzled [rows][128B] LDS tile (bf16: 64 elems/row)
DEVI short8 lds_swz(const u16* base, int row, int colb) {
    int off = (row << 7) + (colb ^ ((row & 7) << 4));
    return *(const short8*)((const char*)base + off);
}

// read one bf16 A-fragment (8 K-elems) from an XOR-swizzled fp32 [128][32] LDS tile
DEVI short8 lds_a_frag(const float* base, int row, int lk) {
    int s0 = (2 * lk) ^ (row & 7);
    int s1 = (2 * lk + 1) ^ (row & 7);
    f32x4 lo = *(const f32x4*)(base + row * 32 + s0 * 4);
    f32x4 hi = *(const f32x4*)(base + row * 32 + s1 * 4);
    return mk8(cvtpk(lo[0], lo[1]), cvtpk(lo[2], lo[3]),
               cvtpk(hi[0], hi[1]), cvtpk(hi[2], hi[3]));
}

// ---------------- weights fp32 -> bf16 (Wq|Wk|Wv|Wo -> contiguous W-region) ----------------
__global__ __launch_bounds__(256) void cvt_w(const float* __restrict__ wq,
                                             const float* __restrict__ wk,
                                             const float* __restrict__ wv,
                                             const float* __restrict__ wo,
                                             u16* __restrict__ dst) {
    int bid = blockIdx.x;  // 2048 blocks: 512 per tensor
    const float* src = bid < 512 ? wq : (bid < 1024 ? wk : (bid < 1536 ? wv : wo));
    int rel = bid & 511;
    size_t base = (size_t)(bid >> 9) * ((size_t)DMODEL * DMODEL);
    size_t i = (size_t)rel * 256 + threadIdx.x;  // 8-elem units
    const float4* p = (const float4*)(src + i * 8);
    float4 a = p[0], c = p[1];
    short8 o;
    o[0] = (short)f2b(a.x); o[1] = (short)f2b(a.y);
    o[2] = (short)f2b(a.z); o[3] = (short)f2b(a.w);
    o[4] = (short)f2b(c.x); o[5] = (short)f2b(c.y);
    o[6] = (short)f2b(c.z); o[7] = (short)f2b(c.w);
    *(short8*)(dst + base + i * 8) = o;
}

// ---------------- fused QKV GEMM: fp32 A via global_load_lds + read-side cvt ----------------
// seg 0: Q = queries@Wq^T (scaled), seg 1: K = keys@Wk^T, seg 2: V = values@Wv^T -> Vt scatter
__global__ __launch_bounds__(256) void gemm_qkv(const float* __restrict__ Xq,
                                                const float* __restrict__ Xk,
                                                const float* __restrict__ Xv,
                                                const u16* __restrict__ W3,
                                                const float* __restrict__ bq,
                                                const float* __restrict__ bk,
                                                const float* __restrict__ bv,
                                                u16* __restrict__ Qp,
                                                u16* __restrict__ Kp,
                                                u16* __restrict__ Vt) {
    __shared__ __align__(16) float Af[2][4096];  // [128 rows][32 K] fp32, slot-XOR swizzled
    __shared__ __align__(16) u16 Bs[2][4096];    // [128 cols][32 K] bf16, linear
    const int tid = threadIdx.x;
    const int lane = tid & 63, w = tid >> 6;
    const int lr = lane & 15, lk = lane >> 4;
    const int wr = w >> 1, wc = w & 1;
    // XCD y-slab swizzle: XCD i owns y in [4i, 4i+4) x all 24 col-tiles (768 = 8*96 bijective)
    const int bid = blockIdx.x;
    const int xcd = bid & 7, rr = bid >> 3;
    const int rb = (xcd * 4 + rr / 24) * 128;
    const int xtile = rr % 24;
    const int cb = xtile * 128;
    const int K = DMODEL;
    const int seg = xtile >> 3;  // 0=Q, 1=K, 2=V (block-uniform)
    const float* A = seg == 0 ? Xq : (seg == 1 ? Xk : Xv);

    f32x4 acc[4][4] = {};

    const int arow = lane >> 2;        // B staging row within 16-row chunk
    const int acol = (lane & 3) * 8;   // B staging k-offset (bf16 elems)

    // A staging: 1024 16B-slots; thread covers slots S_i = (i*4+w)*64 + lane, i=0..3.
    // row = S>>3, slot-in-row = S&7, source slot pre-swizzled (XOR row&7); LDS dest linear.
    const float* Aptr[4];
#pragma unroll
    for (int i = 0; i < 4; ++i) {
        int row = (i * 4 + w) * 8 + (lane >> 3);
        Aptr[i] = A + (size_t)(rb + row) * K + (((lane & 7) ^ (row & 7)) * 4);
    }

#define QKV_STAGE(bb, kk)                                                            \
    do {                                                                             \
        _Pragma("unroll") for (int i = 0; i < 4; ++i)                                \
            async_cp16(Aptr[i] + (kk), &Af[bb][(i * 4 + w) * 256]);                  \
        _Pragma("unroll") for (int c2 = 0; c2 < 2; ++c2) {                           \
            int c = w * 2 + c2;                                                      \
            async_cp16(W3 + (size_t)(cb + c * 16 + arow) * K + (kk) + acol,          \
                       &Bs[bb][c * 512]);                                            \
        }                                                                            \
    } while (0)

    QKV_STAGE(0, 0);
    asm volatile("s_waitcnt vmcnt(0)" ::: "memory");
    __syncthreads();

    int cur = 0;
    for (int k0 = 0; k0 < K; k0 += 32) {
        if (k0 + 32 < K) QKV_STAGE(cur ^ 1, k0 + 32);

        short8 af[4], bfr[4];
#pragma unroll
        for (int m = 0; m < 4; m++)
            af[m] = lds_a_frag(&Af[cur][0], wr * 64 + m * 16 + lr, lk);
#pragma unroll
        for (int n = 0; n < 4; n++)
            bfr[n] = *(const short8*)(&Bs[cur][(wc * 64 + n * 16 + lr) * 32 + lk * 8]);
        __builtin_amdgcn_s_setprio(1);
#pragma unroll
        for (int m = 0; m < 4; m++)
#pragma unroll
            for (int n = 0; n < 4; n++)
                acc[m][n] = __builtin_amdgcn_mfma_f32_16x16x32_bf16(af[m], bfr[n], acc[m][n], 0, 0, 0);
        __builtin_amdgcn_s_setprio(0);

        asm volatile("s_waitcnt vmcnt(0)" ::: "memory");
        __syncthreads();
        cur ^= 1;
    }

    const float* bp = seg == 0 ? bq : (seg == 1 ? bk : bv);
    const float sc = seg == 0 ? QSCALE : 1.0f;

#pragma unroll
    for (int n = 0; n < 4; n++) {
        int col = cb + wc * 64 + n * 16 + lr;
        int c2 = col & 1023;
        float bvv = bp[c2];
#pragma unroll
        for (int m = 0; m < 4; m++) {
            int row0 = rb + wr * 64 + m * 16 + lk * 4;
            if (seg == 2) {
                s16x4 pk4;
#pragma unroll
                for (int r = 0; r < 4; r++) pk4[r] = (short)f2b(acc[m][n][r] + bvv);
                size_t idx = (((size_t)(row0 >> 11) * NH + (c2 >> 6)) * EHD + (c2 & 63)) * LSEQ +
                             (row0 & (LSEQ - 1));
                *(s16x4*)(Vt + idx) = pk4;
            } else {
                u16* dst = seg == 0 ? Qp : Kp;
#pragma unroll
                for (int r = 0; r < 4; r++)
                    dst[(size_t)(row0 + r) * DMODEL + c2] = f2b((acc[m][n][r] + bvv) * sc);
            }
        }
    }
}

// ---------------- output GEMM: depth-2 pipeline, BN=64 tile ----------------
__global__ __launch_bounds__(256) void gemm_out(const u16* __restrict__ A,
                                                const u16* __restrict__ B,
                                                const float* __restrict__ bias,
                                                float* __restrict__ C) {
    __shared__ __align__(16) u16 As[3][4096];
    __shared__ __align__(16) u16 Bs[3][2048];
    const int tid = threadIdx.x;
    const int lane = tid & 63, w = tid >> 6;
    const int lr = lane & 15, lk = lane >> 4;
    const int wr = w >> 1, wc = w & 1;
    // XCD y-slab swizzle (512 = 8*64 bijective)
    const int bid = blockIdx.x;
    const int xcd = bid & 7, rr = bid >> 3;
    const int rb = (xcd * 4 + rr / 16) * 128;
    const int cb = (rr % 16) * 64;
    const int K = DMODEL, N = DMODEL;

    f32x4 acc[4][2] = {};

    const int arow = lane >> 2;
    const int acol = (lane & 3) * 8;

#define OUT_STAGE(bb, kk)                                                           \
    do {                                                                            \
        _Pragma("unroll") for (int c2 = 0; c2 < 2; ++c2) {                          \
            int c = w * 2 + c2;                                                     \
            async_cp16(A + (size_t)(rb + c * 16 + arow) * K + (kk) + acol,          \
                       &As[bb][c * 512]);                                           \
        }                                                                           \
        async_cp16(B + (size_t)(cb + w * 16 + arow) * K + (kk) + acol,              \
                   &Bs[bb][w * 512]);                                               \
    } while (0)

#define OUT_ITER(bc, bs, tt)                                                          \
    do {                                                                              \
        if ((tt) + 2 < 32) OUT_STAGE(bs, ((tt) + 2) * 32);                            \
        short8 af[4], bfr[2];                                                         \
        _Pragma("unroll") for (int m = 0; m < 4; m++)                                 \
            af[m] = *(const short8*)(&As[bc][(wr * 64 + m * 16 + lr) * 32 + lk * 8]); \
        _Pragma("unroll") for (int n = 0; n < 2; n++)                                 \
            bfr[n] = *(const short8*)(&Bs[bc][(wc * 32 + n * 16 + lr) * 32 + lk * 8]); \
        __builtin_amdgcn_s_setprio(1);                                                \
        _Pragma("unroll") for (int m = 0; m < 4; m++)                                 \
            _Pragma("unroll") for (int n = 0; n < 2; n++)                             \
                acc[m][n] =                                                           \
                    __builtin_amdgcn_mfma_f32_16x16x32_bf16(af[m], bfr[n], acc[m][n], 0, 0, 0); \
        __builtin_amdgcn_s_setprio(0);                                                \
        if ((tt) + 2 < 32) asm volatile("s_waitcnt vmcnt(3)" ::: "memory");           \
        else               asm volatile("s_waitcnt vmcnt(0)" ::: "memory");           \
        __builtin_amdgcn_s_barrier();                                                 \
    } while (0)

    OUT_STAGE(0, 0);
    OUT_STAGE(1, 32);
    asm volatile("s_waitcnt vmcnt(3)" ::: "memory");
    __builtin_amdgcn_s_barrier();

    for (int tb = 0; tb < 30; tb += 3) {
        OUT_ITER(0, 2, tb);
        OUT_ITER(1, 0, tb + 1);
        OUT_ITER(2, 1, tb + 2);
    }
    OUT_ITER(0, 2, 30);
    OUT_ITER(1, 0, 31);

#pragma unroll
    for (int n = 0; n < 2; n++) {
        int col = cb + wc * 32 + n * 16 + lr;
        float bv = bias[col];
#pragma unroll
        for (int m = 0; m < 4; m++) {
            int row0 = rb + wr * 64 + m * 16 + lk * 4;
#pragma unroll
            for (int r = 0; r < 4; r++)
                C[(size_t)(row0 + r) * N + col] = acc[m][n][r] + bv;
        }
    }
}

// ---------------- flash attention: QBLK=256 (8 waves), KVBLK=128, fixed-M softmax ----------------
__global__ __launch_bounds__(512) void attn_kernel(const u16* __restrict__ Q,
                                                   const u16* __restrict__ Kp,
                                                   const u16* __restrict__ Vtb,
                                                   u16* __restrict__ Hid) {
    // XCD swizzle: 4 bh per XCD, all 8 q-blocks of one bh on one XCD
    const int bid = blockIdx.x;          // 0..255
    const int j = bid >> 3;              // 0..31
    const int bh = (bid & 7) + 8 * (j >> 3);
    const int q0 = (j & 7) * 256;
    const int b = bh >> 4, h = bh & 15;
    const int tid = threadIdx.x, lane = tid & 63, w = tid >> 6;   // w = 0..7
    const int l31 = lane & 31, hi = lane >> 5;
    const int qb = q0 + w * 32;

    __shared__ __align__(16) u16 Ks[2][8192];     // [128 kv][64 e], xor-swizzled 128B rows
    __shared__ __align__(16) u16 Vs[2][2][4096];  // [kv-half][64 e][64 kv], swizzled rows

    short8 qf[4];
#pragma unroll
    for (int eg = 0; eg < 4; eg++)
        qf[eg] = *(const short8*)(Q + (size_t)(b * LSEQ + qb + l31) * DMODEL + h * EHD +
                                  eg * 16 + hi * 8);

    const int trow = tid >> 3;   // 0..63
    const int slot = tid & 7;    // 16B slot within 128B row
    const int swz8 = ((slot ^ (trow & 7)) * 8);
    size_t kbase[2], vbase[2];
#pragma unroll
    for (int jj = 0; jj < 2; jj++) {
        kbase[jj] = (size_t)(b * LSEQ + jj * 64 + trow) * DMODEL + h * EHD + swz8;
        vbase[jj] = ((size_t)bh * EHD + trow) * LSEQ + jj * 64 + swz8;
    }

#define ATTN_STAGE(bb, s0v)                                                           \
    do {                                                                              \
        async_cp16(Kp + kbase[0] + (size_t)(s0v)*DMODEL, &Ks[bb][w * 512]);           \
        async_cp16(Kp + kbase[1] + (size_t)(s0v)*DMODEL, &Ks[bb][4096 + w * 512]);    \
        async_cp16(Vtb + vbase[0] + (s0v), &Vs[bb][0][w * 512]);                      \
        async_cp16(Vtb + vbase[1] + (s0v), &Vs[bb][1][w * 512]);                      \
    } while (0)

    f32x16 o0 = (f32x16)0.f, o1 = (f32x16)0.f, lsum = (f32x16)0.f;
    const u32 one2 = 0x3F803F80u;  // two bf16 1.0
    const short8 ones = mk8(one2, one2, one2, one2);

    ATTN_STAGE(0, 0);
    asm volatile("s_waitcnt vmcnt(0)" ::: "memory");
    __syncthreads();

    int cur = 0;
    for (int t = 0; t < LSEQ / 128; ++t) {
        if (t + 1 < LSEQ / 128) ATTN_STAGE(cur ^ 1, (t + 1) * 128);

#pragma unroll
        for (int hf = 0; hf < 2; hf++) {
            // ---- QK^T (swapped): S[kv][q] in log2-units, q = l31 ----
            f32x16 s0 = (f32x16)0.f, s1 = (f32x16)0.f;
            __builtin_amdgcn_s_setprio(1);
#pragma unroll
            for (int eg = 0; eg < 4; eg++) {
                short8 kf0 = lds_swz(&Ks[cur][0], hf * 64 + l31, eg * 32 + hi * 16);
                short8 kf1 = lds_swz(&Ks[cur][0], hf * 64 + 32 + l31, eg * 32 + hi * 16);
                s0 = __builtin_amdgcn_mfma_f32_32x32x16_bf16(kf0, qf[eg], s0, 0, 0, 0);
                s1 = __builtin_amdgcn_mfma_f32_32x32x16_bf16(kf1, qf[eg], s1, 0, 0, 0);
            }
            __builtin_amdgcn_s_setprio(0);

            // ---- fixed-M softmax: P = 2^s directly ----
#pragma unroll
            for (int r = 0; r < 16; r++) {
                s0[r] = EXP2(s0[r]);
                s1[r] = EXP2(s1[r]);
            }

            // ---- P -> A-fragments in-register (cvt_pk + permlane32_swap) ----
            short8 paf[4];
#pragma unroll
            for (int kc = 0; kc < 4; kc++) {
                int ro = (kc & 1) * 8;
                u32 u0, u1, u2, u3;
                if (kc < 2) {
                    u0 = cvtpk(s0[ro + 0], s0[ro + 1]); u1 = cvtpk(s0[ro + 2], s0[ro + 3]);
                    u2 = cvtpk(s0[ro + 4], s0[ro + 5]); u3 = cvtpk(s0[ro + 6], s0[ro + 7]);
                } else {
                    u0 = cvtpk(s1[ro + 0], s1[ro + 1]); u1 = cvtpk(s1[ro + 2], s1[ro + 3]);
                    u2 = cvtpk(s1[ro + 4], s1[ro + 5]); u3 = cvtpk(s1[ro + 6], s1[ro + 7]);
                }
                swap32(u0, u2);
                swap32(u1, u3);
                paf[kc] = mk8(u0, u1, u2, u3);
            }

            // ---- PV + l-sum via MFMA (l lands in o-layout) ----
            __builtin_amdgcn_s_setprio(1);
#pragma unroll
            for (int kc = 0; kc < 4; kc++) {
                short8 vf0 = lds_swz(&Vs[cur][hf][0], l31, kc * 32 + hi * 16);
                short8 vf1 = lds_swz(&Vs[cur][hf][0], 32 + l31, kc * 32 + hi * 16);
                o0 = __builtin_amdgcn_mfma_f32_32x32x16_bf16(paf[kc], vf0, o0, 0, 0, 0);
                o1 = __builtin_amdgcn_mfma_f32_32x32x16_bf16(paf[kc], vf1, o1, 0, 0, 0);
                lsum = __builtin_amdgcn_mfma_f32_32x32x16_bf16(paf[kc], ones, lsum, 0, 0, 0);
            }
            __builtin_amdgcn_s_setprio(0);
        }

        asm volatile("s_waitcnt vmcnt(0)" ::: "memory");
        __syncthreads();
        cur ^= 1;
    }

    // ---- epilogue: normalize (lsum already in o-layout) ----
#pragma unroll
    for (int r = 0; r < 16; r++) {
        float li = 1.0f / lsum[r];
        int qrow = qb + (r & 3) + 8 * (r >> 2) + 4 * hi;
        size_t base = (size_t)(b * LSEQ + qrow) * DMODEL + h * EHD;
        Hid[base + l31] = f2b(o0[r] * li);
        Hid[base + 32 + l31] = f2b(o1[r] * li);
    }
}

// ---------------- launch ----------------
extern "C" void kernel_launch(void* const* d_in, const int* in_sizes, int n_in,
                              void* d_out, int out_size, void* d_ws, size_t ws_size,
                              hipStream_t stream) {
    const float* queries = (const float*)d_in[0];
    const float* keys    = (const float*)d_in[1];
    const float* values  = (const float*)d_in[2];
    const float* Wq = (const float*)d_in[3];
    const float* bq = (const float*)d_in[4];
    const float* Wk = (const float*)d_in[5];
    const float* bk = (const float*)d_in[6];
    const float* Wv = (const float*)d_in[7];
    const float* bv = (const float*)d_in[8];
    const float* Wo = (const float*)d_in[9];
    const float* bo = (const float*)d_in[10];
    float* out = (float*)d_out;

    const size_t NX = (size_t)2 * LSEQ * DMODEL;
    const size_t NW = (size_t)DMODEL * DMODEL;

    u16* p = (u16*)d_ws;
    u16* Wqb = p; p += NW;   // Wqb,Wkb,Wvb contiguous => W3 (3072 x 1024); Wob follows
    u16* Wkb = p; p += NW;
    u16* Wvb = p; p += NW;
    u16* Wob = p; p += NW;
    u16* Qp = p;  p += NX;
    u16* Kp = p;  p += NX;
    u16* Vt = p;  p += NX;
    u16* Hid = p; p += NX;
    (void)Wkb; (void)Wvb;

    cvt_w<<<2048, 256, 0, stream>>>(Wq, Wk, Wv, Wo, Wqb);

    gemm_qkv<<<768, 256, 0, stream>>>(queries, keys, values, Wqb, bq, bk, bv, Qp, Kp, Vt);

    attn_kernel<<<256, 512, 0, stream>>>(Qp, Kp, Vt, Hid);

    gemm_out<<<512, 256, 0, stream>>>(Hid, Wob, bo, out);
}

// Round 14
// 131.556 us; speedup vs baseline: 1.0250x; 1.0250x over previous
//
#include <hip/hip_runtime.h>

typedef unsigned short u16;
typedef unsigned int u32;
typedef __attribute__((ext_vector_type(8))) short short8;
typedef __attribute__((ext_vector_type(4))) short s16x4;
typedef __attribute__((ext_vector_type(4))) float f32x4;
typedef __attribute__((ext_vector_type(16))) float f32x16;

#define DEVI __device__ __forceinline__

// B=2, L=S=2048, D=1024, H=16, E=64
#define LSEQ 2048
#define DMODEL 1024
#define NH 16
#define EHD 64

// scores scale folded into Q projection: 1/sqrt(64) * log2(e)
#define QSCALE 0.18033688011112042f

#if __has_builtin(__builtin_amdgcn_exp2f)
#define EXP2(x) __builtin_amdgcn_exp2f(x)
#else
#define EXP2(x) exp2f(x)
#endif

DEVI u16 f2b(float f) {
    u32 u = __float_as_uint(f);
    return (u16)((u + 0x7FFFu + ((u >> 16) & 1u)) >> 16);
}

DEVI u32 cvtpk(float lo, float hi) {
    u32 r;
    asm("v_cvt_pk_bf16_f32 %0, %1, %2" : "=v"(r) : "v"(lo), "v"(hi));
    return r;
}

DEVI void swap32(u32& a, u32& b) {
    asm("v_permlane32_swap_b32 %0, %1" : "+v"(a), "+v"(b));
}

DEVI short8 mk8(u32 a0, u32 a1, u32 a2, u32 a3) {
    union { u32 u[4]; short8 s; } x;
    x.u[0] = a0; x.u[1] = a1; x.u[2] = a2; x.u[3] = a3;
    return x.s;
}

DEVI void async_cp16(const void* g, void* l) {
    __builtin_amdgcn_global_load_lds((const __attribute__((address_space(1))) u32*)g,
                                     (__attribute__((address_space(3))) u32*)l, 16, 0, 0);
}

// read 16B from an XOR-swizzled [rows][128B] LDS tile (bf16: 64 elems/row)
DEVI short8 lds_swz(const u16* base, int row, int colb) {
    int off = (row << 7) + (colb ^ ((row & 7) << 4));
    return *(const short8*)((const char*)base + off);
}

// ---------------- fused fp32 -> bf16 convert (all 7 tensors, 1 launch) ----------------
__global__ __launch_bounds__(256) void cvt_all(const float* __restrict__ q,
                                               const float* __restrict__ k,
                                               const float* __restrict__ v,
                                               const float* __restrict__ wq,
                                               const float* __restrict__ wk,
                                               const float* __restrict__ wv,
                                               const float* __restrict__ wo,
                                               u16* __restrict__ dst) {
    const size_t NX8 = (size_t)2 * LSEQ * DMODEL / 8;
    const size_t NW8 = (size_t)DMODEL * DMODEL / 8;
    int bid = blockIdx.x;
    const float* src;
    size_t base;
    int rel;
    if (bid < 2048)      { src = q;  base = 0;             rel = bid; }
    else if (bid < 4096) { src = k;  base = NX8;           rel = bid - 2048; }
    else if (bid < 6144) { src = v;  base = 2 * NX8;       rel = bid - 4096; }
    else if (bid < 6656) { src = wq; base = 3 * NX8;             rel = bid - 6144; }
    else if (bid < 7168) { src = wk; base = 3 * NX8 + NW8;       rel = bid - 6656; }
    else if (bid < 7680) { src = wv; base = 3 * NX8 + 2 * NW8;   rel = bid - 7168; }
    else                 { src = wo; base = 3 * NX8 + 3 * NW8;   rel = bid - 7680; }
    size_t i = (size_t)rel * 256 + threadIdx.x;
    const float4* p = (const float4*)(src + i * 8);
    float4 a = p[0], c = p[1];
    short8 o;
    o[0] = (short)f2b(a.x); o[1] = (short)f2b(a.y);
    o[2] = (short)f2b(a.z); o[3] = (short)f2b(a.w);
    o[4] = (short)f2b(c.x); o[5] = (short)f2b(c.y);
    o[6] = (short)f2b(c.z); o[7] = (short)f2b(c.w);
    *(short8*)(dst + (base + i) * 8) = o;
}

// ---------------- fused QKV GEMM: 128x64 tiles, 2-buf, 1536 blocks (5-6 blocks/CU) ----------------
__global__ __launch_bounds__(256, 5) void gemm_qkv(const u16* __restrict__ X,
                                                   const u16* __restrict__ W3,
                                                   const float* __restrict__ bq,
                                                   const float* __restrict__ bk,
                                                   const float* __restrict__ bv,
                                                   u16* __restrict__ Qp,
                                                   u16* __restrict__ Kp,
                                                   u16* __restrict__ Vt) {
    __shared__ __align__(16) u16 As[2][4096];  // 128 rows x 32 K
    __shared__ __align__(16) u16 Bs[2][2048];  // 64 cols x 32 K
    const int tid = threadIdx.x;
    const int lane = tid & 63, w = tid >> 6;
    const int lr = lane & 15, lk = lane >> 4;
    const int wr = w >> 1, wc = w & 1;
    // XCD y-slab swizzle: 1536 = 8 XCD x (4 row-slabs x 48 col-tiles), bijective
    const int bid = blockIdx.x;
    const int xcd = bid & 7, rr = bid >> 3;
    const int rb = (xcd * 4 + rr / 48) * 128;
    const int xtile = rr % 48;
    const int cb = xtile * 64;
    const int K = DMODEL;
    const int seg = xtile >> 4;  // 0=Q, 1=K, 2=V (block-uniform)
    const u16* A = X + (size_t)seg * ((size_t)2 * LSEQ * DMODEL);

    f32x4 acc[4][2] = {};

    // staging: A = 512 slots (2/thread), B = 256 slots (1/thread); slot s: row=s>>2, k8=(s&3)*8
    const int sra = tid >> 2, ska = (tid & 3) * 8;

#define QKV_STAGE(bb, kk)                                                            \
    do {                                                                             \
        async_cp16(A + (size_t)(rb + sra) * K + (kk) + ska, &As[bb][tid * 8]);       \
        async_cp16(A + (size_t)(rb + 64 + sra) * K + (kk) + ska,                     \
                   &As[bb][2048 + tid * 8]);                                         \
        async_cp16(W3 + (size_t)(cb + sra) * K + (kk) + ska, &Bs[bb][tid * 8]);      \
    } while (0)

    QKV_STAGE(0, 0);
    asm volatile("s_waitcnt vmcnt(0)" ::: "memory");
    __syncthreads();

    int cur = 0;
    for (int k0 = 0; k0 < K; k0 += 32) {
        if (k0 + 32 < K) QKV_STAGE(cur ^ 1, k0 + 32);

        short8 af[4], bfr[2];
#pragma unroll
        for (int m = 0; m < 4; m++)
            af[m] = *(const short8*)(&As[cur][(wr * 64 + m * 16 + lr) * 32 + lk * 8]);
#pragma unroll
        for (int n = 0; n < 2; n++)
            bfr[n] = *(const short8*)(&Bs[cur][(wc * 32 + n * 16 + lr) * 32 + lk * 8]);
        __builtin_amdgcn_s_setprio(1);
#pragma unroll
        for (int m = 0; m < 4; m++)
#pragma unroll
            for (int n = 0; n < 2; n++)
                acc[m][n] = __builtin_amdgcn_mfma_f32_16x16x32_bf16(af[m], bfr[n], acc[m][n], 0, 0, 0);
        __builtin_amdgcn_s_setprio(0);

        asm volatile("s_waitcnt vmcnt(0)" ::: "memory");
        __syncthreads();
        cur ^= 1;
    }

    const float* bp = seg == 0 ? bq : (seg == 1 ? bk : bv);
    const float sc = seg == 0 ? QSCALE : 1.0f;

#pragma unroll
    for (int n = 0; n < 2; n++) {
        int col = cb + wc * 32 + n * 16 + lr;
        int c2 = col & 1023;
        float bvv = bp[c2];
#pragma unroll
        for (int m = 0; m < 4; m++) {
            int row0 = rb + wr * 64 + m * 16 + lk * 4;
            if (seg == 2) {
                s16x4 pk4;
#pragma unroll
                for (int r = 0; r < 4; r++) pk4[r] = (short)f2b(acc[m][n][r] + bvv);
                size_t idx = (((size_t)(row0 >> 11) * NH + (c2 >> 6)) * EHD + (c2 & 63)) * LSEQ +
                             (row0 & (LSEQ - 1));
                *(s16x4*)(Vt + idx) = pk4;
            } else {
                u16* dst = seg == 0 ? Qp : Kp;
#pragma unroll
                for (int r = 0; r < 4; r++)
                    dst[(size_t)(row0 + r) * DMODEL + c2] = f2b((acc[m][n][r] + bvv) * sc);
            }
        }
    }
}

// ---------------- output GEMM: depth-2 pipeline, BN=64 tile ----------------
__global__ __launch_bounds__(256) void gemm_out(const u16* __restrict__ A,
                                                const u16* __restrict__ B,
                                                const float* __restrict__ bias,
                                                float* __restrict__ C) {
    __shared__ __align__(16) u16 As[3][4096];
    __shared__ __align__(16) u16 Bs[3][2048];
    const int tid = threadIdx.x;
    const int lane = tid & 63, w = tid >> 6;
    const int lr = lane & 15, lk = lane >> 4;
    const int wr = w >> 1, wc = w & 1;
    // XCD y-slab swizzle (512 = 8*64 bijective)
    const int bid = blockIdx.x;
    const int xcd = bid & 7, rr = bid >> 3;
    const int rb = (xcd * 4 + rr / 16) * 128;
    const int cb = (rr % 16) * 64;
    const int K = DMODEL, N = DMODEL;

    f32x4 acc[4][2] = {};

    const int arow = lane >> 2;
    const int acol = (lane & 3) * 8;

#define OUT_STAGE(bb, kk)                                                           \
    do {                                                                            \
        _Pragma("unroll") for (int c2 = 0; c2 < 2; ++c2) {                          \
            int c = w * 2 + c2;                                                     \
            async_cp16(A + (size_t)(rb + c * 16 + arow) * K + (kk) + acol,          \
                       &As[bb][c * 512]);                                           \
        }                                                                           \
        async_cp16(B + (size_t)(cb + w * 16 + arow) * K + (kk) + acol,              \
                   &Bs[bb][w * 512]);                                               \
    } while (0)

#define OUT_ITER(bc, bs, tt)                                                          \
    do {                                                                              \
        if ((tt) + 2 < 32) OUT_STAGE(bs, ((tt) + 2) * 32);                            \
        short8 af[4], bfr[2];                                                         \
        _Pragma("unroll") for (int m = 0; m < 4; m++)                                 \
            af[m] = *(const short8*)(&As[bc][(wr * 64 + m * 16 + lr) * 32 + lk * 8]); \
        _Pragma("unroll") for (int n = 0; n < 2; n++)                                 \
            bfr[n] = *(const short8*)(&Bs[bc][(wc * 32 + n * 16 + lr) * 32 + lk * 8]); \
        __builtin_amdgcn_s_setprio(1);                                                \
        _Pragma("unroll") for (int m = 0; m < 4; m++)                                 \
            _Pragma("unroll") for (int n = 0; n < 2; n++)                             \
                acc[m][n] =                                                           \
                    __builtin_amdgcn_mfma_f32_16x16x32_bf16(af[m], bfr[n], acc[m][n], 0, 0, 0); \
        __builtin_amdgcn_s_setprio(0);                                                \
        if ((tt) + 2 < 32) asm volatile("s_waitcnt vmcnt(3)" ::: "memory");           \
        else               asm volatile("s_waitcnt vmcnt(0)" ::: "memory");           \
        __builtin_amdgcn_s_barrier();                                                 \
    } while (0)

    OUT_STAGE(0, 0);
    OUT_STAGE(1, 32);
    asm volatile("s_waitcnt vmcnt(3)" ::: "memory");
    __builtin_amdgcn_s_barrier();

    for (int tb = 0; tb < 30; tb += 3) {
        OUT_ITER(0, 2, tb);
        OUT_ITER(1, 0, tb + 1);
        OUT_ITER(2, 1, tb + 2);
    }
    OUT_ITER(0, 2, 30);
    OUT_ITER(1, 0, 31);

#pragma unroll
    for (int n = 0; n < 2; n++) {
        int col = cb + wc * 32 + n * 16 + lr;
        float bv = bias[col];
#pragma unroll
        for (int m = 0; m < 4; m++) {
            int row0 = rb + wr * 64 + m * 16 + lk * 4;
#pragma unroll
            for (int r = 0; r < 4; r++)
                C[(size_t)(row0 + r) * N + col] = acc[m][n][r] + bv;
        }
    }
}

// ---------------- flash attention: QBLK=256 (8 waves), KVBLK=128, fixed-M softmax ----------------
__global__ __launch_bounds__(512) void attn_kernel(const u16* __restrict__ Q,
                                                   const u16* __restrict__ Kp,
                                                   const u16* __restrict__ Vtb,
                                                   u16* __restrict__ Hid) {
    // XCD swizzle: 4 bh per XCD, all 8 q-blocks of one bh on one XCD
    const int bid = blockIdx.x;          // 0..255
    const int j = bid >> 3;              // 0..31
    const int bh = (bid & 7) + 8 * (j >> 3);
    const int q0 = (j & 7) * 256;
    const int b = bh >> 4, h = bh & 15;
    const int tid = threadIdx.x, lane = tid & 63, w = tid >> 6;   // w = 0..7
    const int l31 = lane & 31, hi = lane >> 5;
    const int qb = q0 + w * 32;

    __shared__ __align__(16) u16 Ks[2][8192];     // [128 kv][64 e], xor-swizzled 128B rows
    __shared__ __align__(16) u16 Vs[2][2][4096];  // [kv-half][64 e][64 kv], swizzled rows

    short8 qf[4];
#pragma unroll
    for (int eg = 0; eg < 4; eg++)
        qf[eg] = *(const short8*)(Q + (size_t)(b * LSEQ + qb + l31) * DMODEL + h * EHD +
                                  eg * 16 + hi * 8);

    const int trow = tid >> 3;   // 0..63
    const int slot = tid & 7;    // 16B slot within 128B row
    const int swz8 = ((slot ^ (trow & 7)) * 8);
    size_t kbase[2], vbase[2];
#pragma unroll
    for (int jj = 0; jj < 2; jj++) {
        kbase[jj] = (size_t)(b * LSEQ + jj * 64 + trow) * DMODEL + h * EHD + swz8;
        vbase[jj] = ((size_t)bh * EHD + trow) * LSEQ + jj * 64 + swz8;
    }

#define ATTN_STAGE(bb, s0v)                                                           \
    do {                                                                              \
        async_cp16(Kp + kbase[0] + (size_t)(s0v)*DMODEL, &Ks[bb][w * 512]);           \
        async_cp16(Kp + kbase[1] + (size_t)(s0v)*DMODEL, &Ks[bb][4096 + w * 512]);    \
        async_cp16(Vtb + vbase[0] + (s0v), &Vs[bb][0][w * 512]);                      \
        async_cp16(Vtb + vbase[1] + (s0v), &Vs[bb][1][w * 512]);                      \
    } while (0)

    f32x16 o0 = (f32x16)0.f, o1 = (f32x16)0.f, lsum = (f32x16)0.f;
    const u32 one2 = 0x3F803F80u;  // two bf16 1.0
    const short8 ones = mk8(one2, one2, one2, one2);

    ATTN_STAGE(0, 0);
    asm volatile("s_waitcnt vmcnt(0)" ::: "memory");
    __syncthreads();

    int cur = 0;
    for (int t = 0; t < LSEQ / 128; ++t) {
        if (t + 1 < LSEQ / 128) ATTN_STAGE(cur ^ 1, (t + 1) * 128);

#pragma unroll
        for (int hf = 0; hf < 2; hf++) {
            // ---- QK^T (swapped): S[kv][q] in log2-units, q = l31 ----
            f32x16 s0 = (f32x16)0.f, s1 = (f32x16)0.f;
            __builtin_amdgcn_s_setprio(1);
#pragma unroll
            for (int eg = 0; eg < 4; eg++) {
                short8 kf0 = lds_swz(&Ks[cur][0], hf * 64 + l31, eg * 32 + hi * 16);
                short8 kf1 = lds_swz(&Ks[cur][0], hf * 64 + 32 + l31, eg * 32 + hi * 16);
                s0 = __builtin_amdgcn_mfma_f32_32x32x16_bf16(kf0, qf[eg], s0, 0, 0, 0);
                s1 = __builtin_amdgcn_mfma_f32_32x32x16_bf16(kf1, qf[eg], s1, 0, 0, 0);
            }
            __builtin_amdgcn_s_setprio(0);

            // ---- fixed-M softmax: P = 2^s directly ----
#pragma unroll
            for (int r = 0; r < 16; r++) {
                s0[r] = EXP2(s0[r]);
                s1[r] = EXP2(s1[r]);
            }

            // ---- P -> A-fragments in-register (cvt_pk + permlane32_swap) ----
            short8 paf[4];
#pragma unroll
            for (int kc = 0; kc < 4; kc++) {
                int ro = (kc & 1) * 8;
                u32 u0, u1, u2, u3;
                if (kc < 2) {
                    u0 = cvtpk(s0[ro + 0], s0[ro + 1]); u1 = cvtpk(s0[ro + 2], s0[ro + 3]);
                    u2 = cvtpk(s0[ro + 4], s0[ro + 5]); u3 = cvtpk(s0[ro + 6], s0[ro + 7]);
                } else {
                    u0 = cvtpk(s1[ro + 0], s1[ro + 1]); u1 = cvtpk(s1[ro + 2], s1[ro + 3]);
                    u2 = cvtpk(s1[ro + 4], s1[ro + 5]); u3 = cvtpk(s1[ro + 6], s1[ro + 7]);
                }
                swap32(u0, u2);
                swap32(u1, u3);
                paf[kc] = mk8(u0, u1, u2, u3);
            }

            // ---- PV + l-sum via MFMA (l lands in o-layout) ----
            __builtin_amdgcn_s_setprio(1);
#pragma unroll
            for (int kc = 0; kc < 4; kc++) {
                short8 vf0 = lds_swz(&Vs[cur][hf][0], l31, kc * 32 + hi * 16);
                short8 vf1 = lds_swz(&Vs[cur][hf][0], 32 + l31, kc * 32 + hi * 16);
                o0 = __builtin_amdgcn_mfma_f32_32x32x16_bf16(paf[kc], vf0, o0, 0, 0, 0);
                o1 = __builtin_amdgcn_mfma_f32_32x32x16_bf16(paf[kc], vf1, o1, 0, 0, 0);
                lsum = __builtin_amdgcn_mfma_f32_32x32x16_bf16(paf[kc], ones, lsum, 0, 0, 0);
            }
            __builtin_amdgcn_s_setprio(0);
        }

        asm volatile("s_waitcnt vmcnt(0)" ::: "memory");
        __syncthreads();
        cur ^= 1;
    }

    // ---- epilogue: normalize (lsum already in o-layout) ----
#pragma unroll
    for (int r = 0; r < 16; r++) {
        float li = 1.0f / lsum[r];
        int qrow = qb + (r & 3) + 8 * (r >> 2) + 4 * hi;
        size_t base = (size_t)(b * LSEQ + qrow) * DMODEL + h * EHD;
        Hid[base + l31] = f2b(o0[r] * li);
        Hid[base + 32 + l31] = f2b(o1[r] * li);
    }
}

// ---------------- launch ----------------
extern "C" void kernel_launch(void* const* d_in, const int* in_sizes, int n_in,
                              void* d_out, int out_size, void* d_ws, size_t ws_size,
                              hipStream_t stream) {
    const float* queries = (const float*)d_in[0];
    const float* keys    = (const float*)d_in[1];
    const float* values  = (const float*)d_in[2];
    const float* Wq = (const float*)d_in[3];
    const float* bq = (const float*)d_in[4];
    const float* Wk = (const float*)d_in[5];
    const float* bk = (const float*)d_in[6];
    const float* Wv = (const float*)d_in[7];
    const float* bv = (const float*)d_in[8];
    const float* Wo = (const float*)d_in[9];
    const float* bo = (const float*)d_in[10];
    float* out = (float*)d_out;

    const size_t NX = (size_t)2 * LSEQ * DMODEL;
    const size_t NW = (size_t)DMODEL * DMODEL;

    u16* p = (u16*)d_ws;
    u16* Xq = p;  p += NX;   // Xq,Xk,Xv contiguous (indexed by seg in gemm_qkv)
    u16* Xk = p;  p += NX;
    u16* Xv = p;  p += NX;
    u16* Wqb = p; p += NW;   // Wqb,Wkb,Wvb contiguous => W3 (3072 x 1024)
    u16* Wkb = p; p += NW;
    u16* Wvb = p; p += NW;
    u16* Wob = p; p += NW;
    u16* Qp = p;  p += NX;
    u16* Kp = p;  p += NX;
    u16* Vt = p;  p += NX;
    u16* Hid = p; p += NX;
    (void)Xk; (void)Xv; (void)Wkb; (void)Wvb;

    cvt_all<<<8192, 256, 0, stream>>>(queries, keys, values, Wq, Wk, Wv, Wo, Xq);

    gemm_qkv<<<1536, 256, 0, stream>>>(Xq, Wqb, bq, bk, bv, Qp, Kp, Vt);

    attn_kernel<<<256, 512, 0, stream>>>(Qp, Kp, Vt, Hid);

    gemm_out<<<512, 256, 0, stream>>>(Hid, Wob, bo, out);
}

// Round 15
// 117.630 us; speedup vs baseline: 1.1463x; 1.1184x over previous
//
#include <hip/hip_runtime.h>

typedef unsigned short u16;
typedef unsigned int u32;
typedef __attribute__((ext_vector_type(8))) short short8;
typedef __attribute__((ext_vector_type(4))) short s16x4;
typedef __attribute__((ext_vector_type(4))) float f32x4;
typedef __attribute__((ext_vector_type(16))) float f32x16;

#define DEVI __device__ __forceinline__

// B=2, L=S=2048, D=1024, H=16, E=64
#define LSEQ 2048
#define DMODEL 1024
#define NH 16
#define EHD 64

// scores scale folded into Q projection: 1/sqrt(64) * log2(e)
#define QSCALE 0.18033688011112042f

#if __has_builtin(__builtin_amdgcn_exp2f)
#define EXP2(x) __builtin_amdgcn_exp2f(x)
#else
#define EXP2(x) exp2f(x)
#endif

DEVI u16 f2b(float f) {
    u32 u = __float_as_uint(f);
    return (u16)((u + 0x7FFFu + ((u >> 16) & 1u)) >> 16);
}

DEVI u32 cvtpk(float lo, float hi) {
    u32 r;
    asm("v_cvt_pk_bf16_f32 %0, %1, %2" : "=v"(r) : "v"(lo), "v"(hi));
    return r;
}

DEVI void swap32(u32& a, u32& b) {
    asm("v_permlane32_swap_b32 %0, %1" : "+v"(a), "+v"(b));
}

DEVI short8 mk8(u32 a0, u32 a1, u32 a2, u32 a3) {
    union { u32 u[4]; short8 s; } x;
    x.u[0] = a0; x.u[1] = a1; x.u[2] = a2; x.u[3] = a3;
    return x.s;
}

DEVI void async_cp16(const void* g, void* l) {
    __builtin_amdgcn_global_load_lds((const __attribute__((address_space(1))) u32*)g,
                                     (__attribute__((address_space(3))) u32*)l, 16, 0, 0);
}

// read 16B from an XOR-swizzled [rows][128B] LDS tile (bf16: 64 elems/row)
DEVI short8 lds_swz(const u16* base, int row, int colb) {
    int off = (row << 7) + (colb ^ ((row & 7) << 4));
    return *(const short8*)((const char*)base + off);
}

// ---------------- fused fp32 -> bf16 convert (all 7 tensors, 1 launch) ----------------
__global__ __launch_bounds__(256) void cvt_all(const float* __restrict__ q,
                                               const float* __restrict__ k,
                                               const float* __restrict__ v,
                                               const float* __restrict__ wq,
                                               const float* __restrict__ wk,
                                               const float* __restrict__ wv,
                                               const float* __restrict__ wo,
                                               u16* __restrict__ dst) {
    const size_t NX8 = (size_t)2 * LSEQ * DMODEL / 8;
    const size_t NW8 = (size_t)DMODEL * DMODEL / 8;
    int bid = blockIdx.x;
    const float* src;
    size_t base;
    int rel;
    if (bid < 2048)      { src = q;  base = 0;             rel = bid; }
    else if (bid < 4096) { src = k;  base = NX8;           rel = bid - 2048; }
    else if (bid < 6144) { src = v;  base = 2 * NX8;       rel = bid - 4096; }
    else if (bid < 6656) { src = wq; base = 3 * NX8;             rel = bid - 6144; }
    else if (bid < 7168) { src = wk; base = 3 * NX8 + NW8;       rel = bid - 6656; }
    else if (bid < 7680) { src = wv; base = 3 * NX8 + 2 * NW8;   rel = bid - 7168; }
    else                 { src = wo; base = 3 * NX8 + 3 * NW8;   rel = bid - 7680; }
    size_t i = (size_t)rel * 256 + threadIdx.x;
    const float4* p = (const float4*)(src + i * 8);
    float4 a = p[0], c = p[1];
    short8 o;
    o[0] = (short)f2b(a.x); o[1] = (short)f2b(a.y);
    o[2] = (short)f2b(a.z); o[3] = (short)f2b(a.w);
    o[4] = (short)f2b(c.x); o[5] = (short)f2b(c.y);
    o[6] = (short)f2b(c.z); o[7] = (short)f2b(c.w);
    *(short8*)(dst + (base + i) * 8) = o;
}

// ---------------- fused QKV GEMM: 256x256 tile, BK=64, 8 waves, phase-interleaved ----------------
// 16 K-steps; ONE vmcnt(0)+barrier per step, drain covered by ~2.5 phases of compute.
// Race ledger: loads-for-(t+1) -> buf c^1, issued after end-of-(t-1) barrier (all reads of
// c^1 completed before it, consumed by MFMAs) => no WAR. Reads-of-t follow the barrier at
// which every wave drained (vmcnt(0)) its share of buf c => no RAW.
__global__ __launch_bounds__(512, 1) void gemm_qkv(const u16* __restrict__ X,
                                                   const u16* __restrict__ W3,
                                                   const float* __restrict__ bq,
                                                   const float* __restrict__ bk,
                                                   const float* __restrict__ bv,
                                                   u16* __restrict__ Qp,
                                                   u16* __restrict__ Kp,
                                                   u16* __restrict__ Vt) {
    __shared__ __align__(16) u16 As[2][16384];  // [256 rows][64 K] bf16, XOR-swizzled rows
    __shared__ __align__(16) u16 Bs[2][16384];  // [256 cols][64 K] bf16, XOR-swizzled rows
    const int tid = threadIdx.x;
    const int lane = tid & 63;
    const int w = tid >> 6;          // 0..7
    const int lr = lane & 15, lk = lane >> 4;
    const int wm = w >> 2, wn = w & 3;   // 2 x 4 wave grid; wave out = 128 rows x 64 cols
    // XCD swizzle: grid 192 = 8 XCD x 24; XCD i owns 2 row-slabs x 12 col-tiles (bijective)
    const int bid = blockIdx.x;
    const int xcd = bid & 7, rr = bid >> 3;       // rr 0..23
    const int rb = (xcd * 2 + rr / 12) * 256;
    const int cb = (rr % 12) * 256;
    const int K = DMODEL;
    const int seg = cb >> 10;  // 0=Q,1=K,2=V (block-uniform: 1024/256=4 tiles per seg)
    const u16* A = X + (size_t)seg * ((size_t)2 * LSEQ * DMODEL);

    f32x4 acc[8][4] = {};

    // staging: 2048 16B-slots per tile, 4 per thread (chunk i covers slot i*512+tid)
    const int srow = tid >> 3;   // 0..63 within chunk
    const int sslot = tid & 7;
    size_t abase[4], bbase[4];
#pragma unroll
    for (int i = 0; i < 4; i++) {
        int row = i * 64 + srow;
        int swz = ((sslot ^ (row & 7)) * 8);
        abase[i] = (size_t)(rb + row) * K + swz;
        bbase[i] = (size_t)(cb + row) * K + swz;
    }

#define QS_A(bb, kk)                                                         \
    do {                                                                     \
        _Pragma("unroll") for (int i = 0; i < 4; i++)                        \
            async_cp16(A + abase[i] + (kk), &As[bb][(i * 512 + tid) * 8]);   \
    } while (0)
#define QS_B(bb, kk)                                                         \
    do {                                                                     \
        _Pragma("unroll") for (int i = 0; i < 4; i++)                        \
            async_cp16(W3 + bbase[i] + (kk), &Bs[bb][(i * 512 + tid) * 8]);  \
    } while (0)

    // MFMA cluster: m-pair (mt, mt+1) x 4 n x 2 ks  (16 MFMA), A-frags read here
#define QKV_MM(ac_, mt)                                                                   \
    do {                                                                                  \
        short8 a0 = lds_swz(ac_, wm * 128 + (mt) * 16 + lr, lk * 16);                     \
        short8 a1 = lds_swz(ac_, wm * 128 + (mt) * 16 + lr, 64 + lk * 16);                \
        short8 a2 = lds_swz(ac_, wm * 128 + (mt) * 16 + 16 + lr, lk * 16);                \
        short8 a3 = lds_swz(ac_, wm * 128 + (mt) * 16 + 16 + lr, 64 + lk * 16);           \
        __builtin_amdgcn_s_setprio(1);                                                    \
        _Pragma("unroll") for (int n = 0; n < 4; n++) {                                   \
            acc[mt][n] = __builtin_amdgcn_mfma_f32_16x16x32_bf16(a0, bf[n][0], acc[mt][n], 0, 0, 0);       \
            acc[mt][n] = __builtin_amdgcn_mfma_f32_16x16x32_bf16(a1, bf[n][1], acc[mt][n], 0, 0, 0);       \
            acc[(mt) + 1][n] = __builtin_amdgcn_mfma_f32_16x16x32_bf16(a2, bf[n][0], acc[(mt) + 1][n], 0, 0, 0); \
            acc[(mt) + 1][n] = __builtin_amdgcn_mfma_f32_16x16x32_bf16(a3, bf[n][1], acc[(mt) + 1][n], 0, 0, 0); \
        }                                                                                 \
        __builtin_amdgcn_s_setprio(0);                                                    \
    } while (0)

    // prologue: stage K-step 0 into buf 0
    QS_A(0, 0);
    QS_B(0, 0);
    asm volatile("s_waitcnt vmcnt(0)" ::: "memory");
    __builtin_amdgcn_s_barrier();

    int cur = 0;
    for (int t = 0; t < 16; ++t) {
        const u16* ac = &As[cur][0];
        const u16* bc = &Bs[cur][0];
        const bool st = (t + 1 < 16);
        const int kk = (t + 1) * 64;

        // phase 0: stage A(t+1); read all B-frags + MFMA m=0,1
        if (st) QS_A(cur ^ 1, kk);
        short8 bf[4][2];
#pragma unroll
        for (int n = 0; n < 4; n++) {
            bf[n][0] = lds_swz(bc, wn * 64 + n * 16 + lr, lk * 16);
            bf[n][1] = lds_swz(bc, wn * 64 + n * 16 + lr, 64 + lk * 16);
        }
        QKV_MM(ac, 0);
        // phase 1: stage B(t+1); MFMA m=2,3
        if (st) QS_B(cur ^ 1, kk);
        QKV_MM(ac, 2);
        // phases 2-3: MFMA m=4..7 (cover for the in-flight stages)
        QKV_MM(ac, 4);
        QKV_MM(ac, 6);

        asm volatile("s_waitcnt vmcnt(0)" ::: "memory");
        __builtin_amdgcn_s_barrier();
        cur ^= 1;
    }

    const float* bp = seg == 0 ? bq : (seg == 1 ? bk : bv);
    const float sc = seg == 0 ? QSCALE : 1.0f;

#pragma unroll
    for (int n = 0; n < 4; n++) {
        int col = cb + wn * 64 + n * 16 + lr;
        int c2 = col & 1023;
        float bvv = bp[c2];
#pragma unroll
        for (int m = 0; m < 8; m++) {
            int row0 = rb + wm * 128 + m * 16 + lk * 4;
            if (seg == 2) {
                s16x4 pk4;
#pragma unroll
                for (int r = 0; r < 4; r++) pk4[r] = (short)f2b(acc[m][n][r] + bvv);
                size_t idx = (((size_t)(row0 >> 11) * NH + (c2 >> 6)) * EHD + (c2 & 63)) * LSEQ +
                             (row0 & (LSEQ - 1));
                *(s16x4*)(Vt + idx) = pk4;
            } else {
                u16* dst = seg == 0 ? Qp : Kp;
#pragma unroll
                for (int r = 0; r < 4; r++)
                    dst[(size_t)(row0 + r) * DMODEL + c2] = f2b((acc[m][n][r] + bvv) * sc);
            }
        }
    }
}

// ---------------- output GEMM: depth-2 pipeline, BN=64 tile ----------------
__global__ __launch_bounds__(256) void gemm_out(const u16* __restrict__ A,
                                                const u16* __restrict__ B,
                                                const float* __restrict__ bias,
                                                float* __restrict__ C) {
    __shared__ __align__(16) u16 As[3][4096];
    __shared__ __align__(16) u16 Bs[3][2048];
    const int tid = threadIdx.x;
    const int lane = tid & 63, w = tid >> 6;
    const int lr = lane & 15, lk = lane >> 4;
    const int wr = w >> 1, wc = w & 1;
    // XCD y-slab swizzle (512 = 8*64 bijective)
    const int bid = blockIdx.x;
    const int xcd = bid & 7, rr = bid >> 3;
    const int rb = (xcd * 4 + rr / 16) * 128;
    const int cb = (rr % 16) * 64;
    const int K = DMODEL, N = DMODEL;

    f32x4 acc[4][2] = {};

    const int arow = lane >> 2;
    const int acol = (lane & 3) * 8;

#define OUT_STAGE(bb, kk)                                                           \
    do {                                                                            \
        _Pragma("unroll") for (int c2 = 0; c2 < 2; ++c2) {                          \
            int c = w * 2 + c2;                                                     \
            async_cp16(A + (size_t)(rb + c * 16 + arow) * K + (kk) + acol,          \
                       &As[bb][c * 512]);                                           \
        }                                                                           \
        async_cp16(B + (size_t)(cb + w * 16 + arow) * K + (kk) + acol,              \
                   &Bs[bb][w * 512]);                                               \
    } while (0)

#define OUT_ITER(bc, bs, tt)                                                          \
    do {                                                                              \
        if ((tt) + 2 < 32) OUT_STAGE(bs, ((tt) + 2) * 32);                            \
        short8 af[4], bfr[2];                                                         \
        _Pragma("unroll") for (int m = 0; m < 4; m++)                                 \
            af[m] = *(const short8*)(&As[bc][(wr * 64 + m * 16 + lr) * 32 + lk * 8]); \
        _Pragma("unroll") for (int n = 0; n < 2; n++)                                 \
            bfr[n] = *(const short8*)(&Bs[bc][(wc * 32 + n * 16 + lr) * 32 + lk * 8]); \
        __builtin_amdgcn_s_setprio(1);                                                \
        _Pragma("unroll") for (int m = 0; m < 4; m++)                                 \
            _Pragma("unroll") for (int n = 0; n < 2; n++)                             \
                acc[m][n] =                                                           \
                    __builtin_amdgcn_mfma_f32_16x16x32_bf16(af[m], bfr[n], acc[m][n], 0, 0, 0); \
        __builtin_amdgcn_s_setprio(0);                                                \
        if ((tt) + 2 < 32) asm volatile("s_waitcnt vmcnt(3)" ::: "memory");           \
        else               asm volatile("s_waitcnt vmcnt(0)" ::: "memory");           \
        __builtin_amdgcn_s_barrier();                                                 \
    } while (0)

    OUT_STAGE(0, 0);
    OUT_STAGE(1, 32);
    asm volatile("s_waitcnt vmcnt(3)" ::: "memory");
    __builtin_amdgcn_s_barrier();

    for (int tb = 0; tb < 30; tb += 3) {
        OUT_ITER(0, 2, tb);
        OUT_ITER(1, 0, tb + 1);
        OUT_ITER(2, 1, tb + 2);
    }
    OUT_ITER(0, 2, 30);
    OUT_ITER(1, 0, 31);

#pragma unroll
    for (int n = 0; n < 2; n++) {
        int col = cb + wc * 32 + n * 16 + lr;
        float bv = bias[col];
#pragma unroll
        for (int m = 0; m < 4; m++) {
            int row0 = rb + wr * 64 + m * 16 + lk * 4;
#pragma unroll
            for (int r = 0; r < 4; r++)
                C[(size_t)(row0 + r) * N + col] = acc[m][n][r] + bv;
        }
    }
}

// ---------------- flash attention: QBLK=256 (8 waves), KVBLK=128, fixed-M softmax ----------------
__global__ __launch_bounds__(512) void attn_kernel(const u16* __restrict__ Q,
                                                   const u16* __restrict__ Kp,
                                                   const u16* __restrict__ Vtb,
                                                   u16* __restrict__ Hid) {
    // XCD swizzle: 4 bh per XCD, all 8 q-blocks of one bh on one XCD
    const int bid = blockIdx.x;          // 0..255
    const int j = bid >> 3;              // 0..31
    const int bh = (bid & 7) + 8 * (j >> 3);
    const int q0 = (j & 7) * 256;
    const int b = bh >> 4, h = bh & 15;
    const int tid = threadIdx.x, lane = tid & 63, w = tid >> 6;   // w = 0..7
    const int l31 = lane & 31, hi = lane >> 5;
    const int qb = q0 + w * 32;

    __shared__ __align__(16) u16 Ks[2][8192];     // [128 kv][64 e], xor-swizzled 128B rows
    __shared__ __align__(16) u16 Vs[2][2][4096];  // [kv-half][64 e][64 kv], swizzled rows

    short8 qf[4];
#pragma unroll
    for (int eg = 0; eg < 4; eg++)
        qf[eg] = *(const short8*)(Q + (size_t)(b * LSEQ + qb + l31) * DMODEL + h * EHD +
                                  eg * 16 + hi * 8);

    const int trow = tid >> 3;   // 0..63
    const int slot = tid & 7;    // 16B slot within 128B row
    const int swz8 = ((slot ^ (trow & 7)) * 8);
    size_t kbase[2], vbase[2];
#pragma unroll
    for (int jj = 0; jj < 2; jj++) {
        kbase[jj] = (size_t)(b * LSEQ + jj * 64 + trow) * DMODEL + h * EHD + swz8;
        vbase[jj] = ((size_t)bh * EHD + trow) * LSEQ + jj * 64 + swz8;
    }

#define ATTN_STAGE(bb, s0v)                                                           \
    do {                                                                              \
        async_cp16(Kp + kbase[0] + (size_t)(s0v)*DMODEL, &Ks[bb][w * 512]);           \
        async_cp16(Kp + kbase[1] + (size_t)(s0v)*DMODEL, &Ks[bb][4096 + w * 512]);    \
        async_cp16(Vtb + vbase[0] + (s0v), &Vs[bb][0][w * 512]);                      \
        async_cp16(Vtb + vbase[1] + (s0v), &Vs[bb][1][w * 512]);                      \
    } while (0)

    f32x16 o0 = (f32x16)0.f, o1 = (f32x16)0.f, lsum = (f32x16)0.f;
    const u32 one2 = 0x3F803F80u;  // two bf16 1.0
    const short8 ones = mk8(one2, one2, one2, one2);

    ATTN_STAGE(0, 0);
    asm volatile("s_waitcnt vmcnt(0)" ::: "memory");
    __syncthreads();

    int cur = 0;
    for (int t = 0; t < LSEQ / 128; ++t) {
        if (t + 1 < LSEQ / 128) ATTN_STAGE(cur ^ 1, (t + 1) * 128);

#pragma unroll
        for (int hf = 0; hf < 2; hf++) {
            // ---- QK^T (swapped): S[kv][q] in log2-units, q = l31 ----
            f32x16 s0 = (f32x16)0.f, s1 = (f32x16)0.f;
            __builtin_amdgcn_s_setprio(1);
#pragma unroll
            for (int eg = 0; eg < 4; eg++) {
                short8 kf0 = lds_swz(&Ks[cur][0], hf * 64 + l31, eg * 32 + hi * 16);
                short8 kf1 = lds_swz(&Ks[cur][0], hf * 64 + 32 + l31, eg * 32 + hi * 16);
                s0 = __builtin_amdgcn_mfma_f32_32x32x16_bf16(kf0, qf[eg], s0, 0, 0, 0);
                s1 = __builtin_amdgcn_mfma_f32_32x32x16_bf16(kf1, qf[eg], s1, 0, 0, 0);
            }
            __builtin_amdgcn_s_setprio(0);

            // ---- fixed-M softmax: P = 2^s directly ----
#pragma unroll
            for (int r = 0; r < 16; r++) {
                s0[r] = EXP2(s0[r]);
                s1[r] = EXP2(s1[r]);
            }

            // ---- P -> A-fragments in-register (cvt_pk + permlane32_swap) ----
            short8 paf[4];
#pragma unroll
            for (int kc = 0; kc < 4; kc++) {
                int ro = (kc & 1) * 8;
                u32 u0, u1, u2, u3;
                if (kc < 2) {
                    u0 = cvtpk(s0[ro + 0], s0[ro + 1]); u1 = cvtpk(s0[ro + 2], s0[ro + 3]);
                    u2 = cvtpk(s0[ro + 4], s0[ro + 5]); u3 = cvtpk(s0[ro + 6], s0[ro + 7]);
                } else {
                    u0 = cvtpk(s1[ro + 0], s1[ro + 1]); u1 = cvtpk(s1[ro + 2], s1[ro + 3]);
                    u2 = cvtpk(s1[ro + 4], s1[ro + 5]); u3 = cvtpk(s1[ro + 6], s1[ro + 7]);
                }
                swap32(u0, u2);
                swap32(u1, u3);
                paf[kc] = mk8(u0, u1, u2, u3);
            }

            // ---- PV + l-sum via MFMA (l lands in o-layout) ----
            __builtin_amdgcn_s_setprio(1);
#pragma unroll
            for (int kc = 0; kc < 4; kc++) {
                short8 vf0 = lds_swz(&Vs[cur][hf][0], l31, kc * 32 + hi * 16);
                short8 vf1 = lds_swz(&Vs[cur][hf][0], 32 + l31, kc * 32 + hi * 16);
                o0 = __builtin_amdgcn_mfma_f32_32x32x16_bf16(paf[kc], vf0, o0, 0, 0, 0);
                o1 = __builtin_amdgcn_mfma_f32_32x32x16_bf16(paf[kc], vf1, o1, 0, 0, 0);
                lsum = __builtin_amdgcn_mfma_f32_32x32x16_bf16(paf[kc], ones, lsum, 0, 0, 0);
            }
            __builtin_amdgcn_s_setprio(0);
        }

        asm volatile("s_waitcnt vmcnt(0)" ::: "memory");
        __syncthreads();
        cur ^= 1;
    }

    // ---- epilogue: normalize (lsum already in o-layout) ----
#pragma unroll
    for (int r = 0; r < 16; r++) {
        float li = 1.0f / lsum[r];
        int qrow = qb + (r & 3) + 8 * (r >> 2) + 4 * hi;
        size_t base = (size_t)(b * LSEQ + qrow) * DMODEL + h * EHD;
        Hid[base + l31] = f2b(o0[r] * li);
        Hid[base + 32 + l31] = f2b(o1[r] * li);
    }
}

// ---------------- launch ----------------
extern "C" void kernel_launch(void* const* d_in, const int* in_sizes, int n_in,
                              void* d_out, int out_size, void* d_ws, size_t ws_size,
                              hipStream_t stream) {
    const float* queries = (const float*)d_in[0];
    const float* keys    = (const float*)d_in[1];
    const float* values  = (const float*)d_in[2];
    const float* Wq = (const float*)d_in[3];
    const float* bq = (const float*)d_in[4];
    const float* Wk = (const float*)d_in[5];
    const float* bk = (const float*)d_in[6];
    const float* Wv = (const float*)d_in[7];
    const float* bv = (const float*)d_in[8];
    const float* Wo = (const float*)d_in[9];
    const float* bo = (const float*)d_in[10];
    float* out = (float*)d_out;

    const size_t NX = (size_t)2 * LSEQ * DMODEL;
    const size_t NW = (size_t)DMODEL * DMODEL;

    u16* p = (u16*)d_ws;
    u16* Xq = p;  p += NX;   // Xq,Xk,Xv contiguous (indexed by seg in gemm_qkv)
    u16* Xk = p;  p += NX;
    u16* Xv = p;  p += NX;
    u16* Wqb = p; p += NW;   // Wqb,Wkb,Wvb contiguous => W3 (3072 x 1024)
    u16* Wkb = p; p += NW;
    u16* Wvb = p; p += NW;
    u16* Wob = p; p += NW;
    u16* Qp = p;  p += NX;
    u16* Kp = p;  p += NX;
    u16* Vt = p;  p += NX;
    u16* Hid = p; p += NX;
    (void)Xk; (void)Xv; (void)Wkb; (void)Wvb;

    cvt_all<<<8192, 256, 0, stream>>>(queries, keys, values, Wq, Wk, Wv, Wo, Xq);

    gemm_qkv<<<192, 512, 0, stream>>>(Xq, Wqb, bq, bk, bv, Qp, Kp, Vt);

    attn_kernel<<<256, 512, 0, stream>>>(Qp, Kp, Vt, Hid);

    gemm_out<<<512, 256, 0, stream>>>(Hid, Wob, bo, out);
}

// Round 16
// 115.996 us; speedup vs baseline: 1.1625x; 1.0141x over previous
//
#include <hip/hip_runtime.h>

typedef unsigned short u16;
typedef unsigned int u32;
typedef __attribute__((ext_vector_type(8))) short short8;
typedef __attribute__((ext_vector_type(4))) short s16x4;
typedef __attribute__((ext_vector_type(4))) float f32x4;
typedef __attribute__((ext_vector_type(16))) float f32x16;

#define DEVI __device__ __forceinline__

// B=2, L=S=2048, D=1024, H=16, E=64
#define LSEQ 2048
#define DMODEL 1024
#define NH 16
#define EHD 64

// scores scale folded into Q projection: 1/sqrt(64) * log2(e)
#define QSCALE 0.18033688011112042f

#if __has_builtin(__builtin_amdgcn_exp2f)
#define EXP2(x) __builtin_amdgcn_exp2f(x)
#else
#define EXP2(x) exp2f(x)
#endif

DEVI u16 f2b(float f) {
    u32 u = __float_as_uint(f);
    return (u16)((u + 0x7FFFu + ((u >> 16) & 1u)) >> 16);
}

DEVI u32 cvtpk(float lo, float hi) {
    u32 r;
    asm("v_cvt_pk_bf16_f32 %0, %1, %2" : "=v"(r) : "v"(lo), "v"(hi));
    return r;
}

DEVI void swap32(u32& a, u32& b) {
    asm("v_permlane32_swap_b32 %0, %1" : "+v"(a), "+v"(b));
}

DEVI short8 mk8(u32 a0, u32 a1, u32 a2, u32 a3) {
    union { u32 u[4]; short8 s; } x;
    x.u[0] = a0; x.u[1] = a1; x.u[2] = a2; x.u[3] = a3;
    return x.s;
}

DEVI void async_cp16(const void* g, void* l) {
    __builtin_amdgcn_global_load_lds((const __attribute__((address_space(1))) u32*)g,
                                     (__attribute__((address_space(3))) u32*)l, 16, 0, 0);
}

// read 16B from an XOR-swizzled [rows][128B] LDS tile (bf16: 64 elems/row)
DEVI short8 lds_swz(const u16* base, int row, int colb) {
    int off = (row << 7) + (colb ^ ((row & 7) << 4));
    return *(const short8*)((const char*)base + off);
}

// ---------------- fused fp32 -> bf16 convert (all 7 tensors, 1 launch) ----------------
__global__ __launch_bounds__(256) void cvt_all(const float* __restrict__ q,
                                               const float* __restrict__ k,
                                               const float* __restrict__ v,
                                               const float* __restrict__ wq,
                                               const float* __restrict__ wk,
                                               const float* __restrict__ wv,
                                               const float* __restrict__ wo,
                                               u16* __restrict__ dst) {
    const size_t NX8 = (size_t)2 * LSEQ * DMODEL / 8;
    const size_t NW8 = (size_t)DMODEL * DMODEL / 8;
    int bid = blockIdx.x;
    const float* src;
    size_t base;
    int rel;
    if (bid < 2048)      { src = q;  base = 0;             rel = bid; }
    else if (bid < 4096) { src = k;  base = NX8;           rel = bid - 2048; }
    else if (bid < 6144) { src = v;  base = 2 * NX8;       rel = bid - 4096; }
    else if (bid < 6656) { src = wq; base = 3 * NX8;             rel = bid - 6144; }
    else if (bid < 7168) { src = wk; base = 3 * NX8 + NW8;       rel = bid - 6656; }
    else if (bid < 7680) { src = wv; base = 3 * NX8 + 2 * NW8;   rel = bid - 7168; }
    else                 { src = wo; base = 3 * NX8 + 3 * NW8;   rel = bid - 7680; }
    size_t i = (size_t)rel * 256 + threadIdx.x;
    const float4* p = (const float4*)(src + i * 8);
    float4 a = p[0], c = p[1];
    short8 o;
    o[0] = (short)f2b(a.x); o[1] = (short)f2b(a.y);
    o[2] = (short)f2b(a.z); o[3] = (short)f2b(a.w);
    o[4] = (short)f2b(c.x); o[5] = (short)f2b(c.y);
    o[6] = (short)f2b(c.z); o[7] = (short)f2b(c.w);
    *(short8*)(dst + (base + i) * 8) = o;
}

// ---------------- fused QKV GEMM: 256x256 tile, BK=64, 8 waves, phase-interleaved ----------------
__global__ __launch_bounds__(512, 1) void gemm_qkv(const u16* __restrict__ X,
                                                   const u16* __restrict__ W3,
                                                   const float* __restrict__ bq,
                                                   const float* __restrict__ bk,
                                                   const float* __restrict__ bv,
                                                   u16* __restrict__ Qp,
                                                   u16* __restrict__ Kp,
                                                   u16* __restrict__ Vt) {
    __shared__ __align__(16) u16 As[2][16384];  // [256 rows][64 K] bf16, XOR-swizzled rows
    __shared__ __align__(16) u16 Bs[2][16384];  // [256 cols][64 K] bf16, XOR-swizzled rows
    const int tid = threadIdx.x;
    const int lane = tid & 63;
    const int w = tid >> 6;          // 0..7
    const int lr = lane & 15, lk = lane >> 4;
    const int wm = w >> 2, wn = w & 3;   // 2 x 4 wave grid; wave out = 128 rows x 64 cols
    // XCD swizzle: grid 192 = 8 XCD x 24; XCD i owns 2 row-slabs x 12 col-tiles (bijective)
    const int bid = blockIdx.x;
    const int xcd = bid & 7, rr = bid >> 3;       // rr 0..23
    const int rb = (xcd * 2 + rr / 12) * 256;
    const int cb = (rr % 12) * 256;
    const int K = DMODEL;
    const int seg = cb >> 10;  // 0=Q,1=K,2=V (block-uniform: 1024/256=4 tiles per seg)
    const u16* A = X + (size_t)seg * ((size_t)2 * LSEQ * DMODEL);

    f32x4 acc[8][4] = {};

    // staging: 2048 16B-slots per tile, 4 per thread (chunk i covers slot i*512+tid)
    const int srow = tid >> 3;   // 0..63 within chunk
    const int sslot = tid & 7;
    size_t abase[4], bbase[4];
#pragma unroll
    for (int i = 0; i < 4; i++) {
        int row = i * 64 + srow;
        int swz = ((sslot ^ (row & 7)) * 8);
        abase[i] = (size_t)(rb + row) * K + swz;
        bbase[i] = (size_t)(cb + row) * K + swz;
    }

#define QS_A(bb, kk)                                                         \
    do {                                                                     \
        _Pragma("unroll") for (int i = 0; i < 4; i++)                        \
            async_cp16(A + abase[i] + (kk), &As[bb][(i * 512 + tid) * 8]);   \
    } while (0)
#define QS_B(bb, kk)                                                         \
    do {                                                                     \
        _Pragma("unroll") for (int i = 0; i < 4; i++)                        \
            async_cp16(W3 + bbase[i] + (kk), &Bs[bb][(i * 512 + tid) * 8]);  \
    } while (0)

    // MFMA cluster: m-pair (mt, mt+1) x 4 n x 2 ks  (16 MFMA), A-frags read here
#define QKV_MM(ac_, mt)                                                                   \
    do {                                                                                  \
        short8 a0 = lds_swz(ac_, wm * 128 + (mt) * 16 + lr, lk * 16);                     \
        short8 a1 = lds_swz(ac_, wm * 128 + (mt) * 16 + lr, 64 + lk * 16);                \
        short8 a2 = lds_swz(ac_, wm * 128 + (mt) * 16 + 16 + lr, lk * 16);                \
        short8 a3 = lds_swz(ac_, wm * 128 + (mt) * 16 + 16 + lr, 64 + lk * 16);           \
        __builtin_amdgcn_s_setprio(1);                                                    \
        _Pragma("unroll") for (int n = 0; n < 4; n++) {                                   \
            acc[mt][n] = __builtin_amdgcn_mfma_f32_16x16x32_bf16(a0, bf[n][0], acc[mt][n], 0, 0, 0);       \
            acc[mt][n] = __builtin_amdgcn_mfma_f32_16x16x32_bf16(a1, bf[n][1], acc[mt][n], 0, 0, 0);       \
            acc[(mt) + 1][n] = __builtin_amdgcn_mfma_f32_16x16x32_bf16(a2, bf[n][0], acc[(mt) + 1][n], 0, 0, 0); \
            acc[(mt) + 1][n] = __builtin_amdgcn_mfma_f32_16x16x32_bf16(a3, bf[n][1], acc[(mt) + 1][n], 0, 0, 0); \
        }                                                                                 \
        __builtin_amdgcn_s_setprio(0);                                                    \
    } while (0)

    // prologue: stage K-step 0 into buf 0
    QS_A(0, 0);
    QS_B(0, 0);
    asm volatile("s_waitcnt vmcnt(0)" ::: "memory");
    __builtin_amdgcn_s_barrier();

    int cur = 0;
    for (int t = 0; t < 16; ++t) {
        const u16* ac = &As[cur][0];
        const u16* bc = &Bs[cur][0];
        const bool st = (t + 1 < 16);
        const int kk = (t + 1) * 64;

        // phase 0: stage A(t+1); read all B-frags + MFMA m=0,1
        if (st) QS_A(cur ^ 1, kk);
        short8 bf[4][2];
#pragma unroll
        for (int n = 0; n < 4; n++) {
            bf[n][0] = lds_swz(bc, wn * 64 + n * 16 + lr, lk * 16);
            bf[n][1] = lds_swz(bc, wn * 64 + n * 16 + lr, 64 + lk * 16);
        }
        QKV_MM(ac, 0);
        // phase 1: stage B(t+1); MFMA m=2,3
        if (st) QS_B(cur ^ 1, kk);
        QKV_MM(ac, 2);
        // phases 2-3: MFMA m=4..7 (cover for the in-flight stages)
        QKV_MM(ac, 4);
        QKV_MM(ac, 6);

        asm volatile("s_waitcnt vmcnt(0)" ::: "memory");
        __builtin_amdgcn_s_barrier();
        cur ^= 1;
    }

    const float* bp = seg == 0 ? bq : (seg == 1 ? bk : bv);
    const float sc = seg == 0 ? QSCALE : 1.0f;

#pragma unroll
    for (int n = 0; n < 4; n++) {
        int col = cb + wn * 64 + n * 16 + lr;
        int c2 = col & 1023;
        float bvv = bp[c2];
#pragma unroll
        for (int m = 0; m < 8; m++) {
            int row0 = rb + wm * 128 + m * 16 + lk * 4;
            if (seg == 2) {
                s16x4 pk4;
#pragma unroll
                for (int r = 0; r < 4; r++) pk4[r] = (short)f2b(acc[m][n][r] + bvv);
                size_t idx = (((size_t)(row0 >> 11) * NH + (c2 >> 6)) * EHD + (c2 & 63)) * LSEQ +
                             (row0 & (LSEQ - 1));
                *(s16x4*)(Vt + idx) = pk4;
            } else {
                u16* dst = seg == 0 ? Qp : Kp;
#pragma unroll
                for (int r = 0; r < 4; r++)
                    dst[(size_t)(row0 + r) * DMODEL + c2] = f2b((acc[m][n][r] + bvv) * sc);
            }
        }
    }
}

// ---------------- output GEMM: depth-2 pipeline, BN=64 tile ----------------
__global__ __launch_bounds__(256) void gemm_out(const u16* __restrict__ A,
                                                const u16* __restrict__ B,
                                                const float* __restrict__ bias,
                                                float* __restrict__ C) {
    __shared__ __align__(16) u16 As[3][4096];
    __shared__ __align__(16) u16 Bs[3][2048];
    const int tid = threadIdx.x;
    const int lane = tid & 63, w = tid >> 6;
    const int lr = lane & 15, lk = lane >> 4;
    const int wr = w >> 1, wc = w & 1;
    // XCD y-slab swizzle (512 = 8*64 bijective)
    const int bid = blockIdx.x;
    const int xcd = bid & 7, rr = bid >> 3;
    const int rb = (xcd * 4 + rr / 16) * 128;
    const int cb = (rr % 16) * 64;
    const int K = DMODEL, N = DMODEL;

    f32x4 acc[4][2] = {};

    const int arow = lane >> 2;
    const int acol = (lane & 3) * 8;

#define OUT_STAGE(bb, kk)                                                           \
    do {                                                                            \
        _Pragma("unroll") for (int c2 = 0; c2 < 2; ++c2) {                          \
            int c = w * 2 + c2;                                                     \
            async_cp16(A + (size_t)(rb + c * 16 + arow) * K + (kk) + acol,          \
                       &As[bb][c * 512]);                                           \
        }                                                                           \
        async_cp16(B + (size_t)(cb + w * 16 + arow) * K + (kk) + acol,              \
                   &Bs[bb][w * 512]);                                               \
    } while (0)

#define OUT_ITER(bc, bs, tt)                                                          \
    do {                                                                              \
        if ((tt) + 2 < 32) OUT_STAGE(bs, ((tt) + 2) * 32);                            \
        short8 af[4], bfr[2];                                                         \
        _Pragma("unroll") for (int m = 0; m < 4; m++)                                 \
            af[m] = *(const short8*)(&As[bc][(wr * 64 + m * 16 + lr) * 32 + lk * 8]); \
        _Pragma("unroll") for (int n = 0; n < 2; n++)                                 \
            bfr[n] = *(const short8*)(&Bs[bc][(wc * 32 + n * 16 + lr) * 32 + lk * 8]); \
        __builtin_amdgcn_s_setprio(1);                                                \
        _Pragma("unroll") for (int m = 0; m < 4; m++)                                 \
            _Pragma("unroll") for (int n = 0; n < 2; n++)                             \
                acc[m][n] =                                                           \
                    __builtin_amdgcn_mfma_f32_16x16x32_bf16(af[m], bfr[n], acc[m][n], 0, 0, 0); \
        __builtin_amdgcn_s_setprio(0);                                                \
        if ((tt) + 2 < 32) asm volatile("s_waitcnt vmcnt(3)" ::: "memory");           \
        else               asm volatile("s_waitcnt vmcnt(0)" ::: "memory");           \
        __builtin_amdgcn_s_barrier();                                                 \
    } while (0)

    OUT_STAGE(0, 0);
    OUT_STAGE(1, 32);
    asm volatile("s_waitcnt vmcnt(3)" ::: "memory");
    __builtin_amdgcn_s_barrier();

    for (int tb = 0; tb < 30; tb += 3) {
        OUT_ITER(0, 2, tb);
        OUT_ITER(1, 0, tb + 1);
        OUT_ITER(2, 1, tb + 2);
    }
    OUT_ITER(0, 2, 30);
    OUT_ITER(1, 0, 31);

#pragma unroll
    for (int n = 0; n < 2; n++) {
        int col = cb + wc * 32 + n * 16 + lr;
        float bv = bias[col];
#pragma unroll
        for (int m = 0; m < 4; m++) {
            int row0 = rb + wr * 64 + m * 16 + lk * 4;
#pragma unroll
            for (int r = 0; r < 4; r++)
                C[(size_t)(row0 + r) * N + col] = acc[m][n][r] + bv;
        }
    }
}

// ---------------- flash attention: QBLK=256 (8 waves), KVBLK=256, fixed-M softmax ----------------
// KVBLK=256: one stage (8 loads/thread) + one drain + one barrier per 256 kv — half the
// sync events of KVBLK=128, and a 4-subtile unrolled body for compiler ILP. LDS 128 KB.
__global__ __launch_bounds__(512, 1) void attn_kernel(const u16* __restrict__ Q,
                                                      const u16* __restrict__ Kp,
                                                      const u16* __restrict__ Vtb,
                                                      u16* __restrict__ Hid) {
    // XCD swizzle: 4 bh per XCD, all 8 q-blocks of one bh on one XCD
    const int bid = blockIdx.x;          // 0..255
    const int j = bid >> 3;              // 0..31
    const int bh = (bid & 7) + 8 * (j >> 3);
    const int q0 = (j & 7) * 256;
    const int b = bh >> 4, h = bh & 15;
    const int tid = threadIdx.x, lane = tid & 63, w = tid >> 6;   // w = 0..7
    const int l31 = lane & 31, hi = lane >> 5;
    const int qb = q0 + w * 32;

    __shared__ __align__(16) u16 Ks[2][16384];    // [256 kv][64 e], xor-swizzled 128B rows
    __shared__ __align__(16) u16 Vs[2][4][4096];  // [kv-quarter][64 e][64 kv], swizzled rows

    short8 qf[4];
#pragma unroll
    for (int eg = 0; eg < 4; eg++)
        qf[eg] = *(const short8*)(Q + (size_t)(b * LSEQ + qb + l31) * DMODEL + h * EHD +
                                  eg * 16 + hi * 8);

    const int trow = tid >> 3;   // 0..63
    const int slot = tid & 7;    // 16B slot within 128B row
    const int swz8 = ((slot ^ (trow & 7)) * 8);
    size_t kbase[4], vbase[4];
#pragma unroll
    for (int jj = 0; jj < 4; jj++) {
        kbase[jj] = (size_t)(b * LSEQ + jj * 64 + trow) * DMODEL + h * EHD + swz8;
        vbase[jj] = ((size_t)bh * EHD + trow) * LSEQ + jj * 64 + swz8;
    }

#define ATTN_STAGE(bb, s0v)                                                              \
    do {                                                                                 \
        _Pragma("unroll") for (int jj = 0; jj < 4; jj++)                                 \
            async_cp16(Kp + kbase[jj] + (size_t)(s0v)*DMODEL,                            \
                       &Ks[bb][jj * 4096 + w * 512]);                                    \
        _Pragma("unroll") for (int jj = 0; jj < 4; jj++)                                 \
            async_cp16(Vtb + vbase[jj] + (s0v), &Vs[bb][jj][w * 512]);                   \
    } while (0)

    f32x16 o0 = (f32x16)0.f, o1 = (f32x16)0.f, lsum = (f32x16)0.f;
    const u32 one2 = 0x3F803F80u;  // two bf16 1.0
    const short8 ones = mk8(one2, one2, one2, one2);

    ATTN_STAGE(0, 0);
    asm volatile("s_waitcnt vmcnt(0)" ::: "memory");
    __syncthreads();

    int cur = 0;
    for (int t = 0; t < LSEQ / 256; ++t) {
        if (t + 1 < LSEQ / 256) ATTN_STAGE(cur ^ 1, (t + 1) * 256);

#pragma unroll
        for (int hf = 0; hf < 4; hf++) {
            // ---- QK^T (swapped): S[kv][q] in log2-units, q = l31 ----
            f32x16 s0 = (f32x16)0.f, s1 = (f32x16)0.f;
            __builtin_amdgcn_s_setprio(1);
#pragma unroll
            for (int eg = 0; eg < 4; eg++) {
                short8 kf0 = lds_swz(&Ks[cur][0], hf * 64 + l31, eg * 32 + hi * 16);
                short8 kf1 = lds_swz(&Ks[cur][0], hf * 64 + 32 + l31, eg * 32 + hi * 16);
                s0 = __builtin_amdgcn_mfma_f32_32x32x16_bf16(kf0, qf[eg], s0, 0, 0, 0);
                s1 = __builtin_amdgcn_mfma_f32_32x32x16_bf16(kf1, qf[eg], s1, 0, 0, 0);
            }
            __builtin_amdgcn_s_setprio(0);

            // ---- fixed-M softmax: P = 2^s directly ----
#pragma unroll
            for (int r = 0; r < 16; r++) {
                s0[r] = EXP2(s0[r]);
                s1[r] = EXP2(s1[r]);
            }

            // ---- P -> A-fragments in-register (cvt_pk + permlane32_swap) ----
            short8 paf[4];
#pragma unroll
            for (int kc = 0; kc < 4; kc++) {
                int ro = (kc & 1) * 8;
                u32 u0, u1, u2, u3;
                if (kc < 2) {
                    u0 = cvtpk(s0[ro + 0], s0[ro + 1]); u1 = cvtpk(s0[ro + 2], s0[ro + 3]);
                    u2 = cvtpk(s0[ro + 4], s0[ro + 5]); u3 = cvtpk(s0[ro + 6], s0[ro + 7]);
                } else {
                    u0 = cvtpk(s1[ro + 0], s1[ro + 1]); u1 = cvtpk(s1[ro + 2], s1[ro + 3]);
                    u2 = cvtpk(s1[ro + 4], s1[ro + 5]); u3 = cvtpk(s1[ro + 6], s1[ro + 7]);
                }
                swap32(u0, u2);
                swap32(u1, u3);
                paf[kc] = mk8(u0, u1, u2, u3);
            }

            // ---- PV + l-sum via MFMA (l lands in o-layout) ----
            __builtin_amdgcn_s_setprio(1);
#pragma unroll
            for (int kc = 0; kc < 4; kc++) {
                short8 vf0 = lds_swz(&Vs[cur][hf][0], l31, kc * 32 + hi * 16);
                short8 vf1 = lds_swz(&Vs[cur][hf][0], 32 + l31, kc * 32 + hi * 16);
                o0 = __builtin_amdgcn_mfma_f32_32x32x16_bf16(paf[kc], vf0, o0, 0, 0, 0);
                o1 = __builtin_amdgcn_mfma_f32_32x32x16_bf16(paf[kc], vf1, o1, 0, 0, 0);
                lsum = __builtin_amdgcn_mfma_f32_32x32x16_bf16(paf[kc], ones, lsum, 0, 0, 0);
            }
            __builtin_amdgcn_s_setprio(0);
        }

        asm volatile("s_waitcnt vmcnt(0)" ::: "memory");
        __syncthreads();
        cur ^= 1;
    }

    // ---- epilogue: normalize (lsum already in o-layout) ----
#pragma unroll
    for (int r = 0; r < 16; r++) {
        float li = 1.0f / lsum[r];
        int qrow = qb + (r & 3) + 8 * (r >> 2) + 4 * hi;
        size_t base = (size_t)(b * LSEQ + qrow) * DMODEL + h * EHD;
        Hid[base + l31] = f2b(o0[r] * li);
        Hid[base + 32 + l31] = f2b(o1[r] * li);
    }
}

// ---------------- launch ----------------
extern "C" void kernel_launch(void* const* d_in, const int* in_sizes, int n_in,
                              void* d_out, int out_size, void* d_ws, size_t ws_size,
                              hipStream_t stream) {
    const float* queries = (const float*)d_in[0];
    const float* keys    = (const float*)d_in[1];
    const float* values  = (const float*)d_in[2];
    const float* Wq = (const float*)d_in[3];
    const float* bq = (const float*)d_in[4];
    const float* Wk = (const float*)d_in[5];
    const float* bk = (const float*)d_in[6];
    const float* Wv = (const float*)d_in[7];
    const float* bv = (const float*)d_in[8];
    const float* Wo = (const float*)d_in[9];
    const float* bo = (const float*)d_in[10];
    float* out = (float*)d_out;

    const size_t NX = (size_t)2 * LSEQ * DMODEL;
    const size_t NW = (size_t)DMODEL * DMODEL;

    u16* p = (u16*)d_ws;
    u16* Xq = p;  p += NX;   // Xq,Xk,Xv contiguous (indexed by seg in gemm_qkv)
    u16* Xk = p;  p += NX;
    u16* Xv = p;  p += NX;
    u16* Wqb = p; p += NW;   // Wqb,Wkb,Wvb contiguous => W3 (3072 x 1024)
    u16* Wkb = p; p += NW;
    u16* Wvb = p; p += NW;
    u16* Wob = p; p += NW;
    u16* Qp = p;  p += NX;
    u16* Kp = p;  p += NX;
    u16* Vt = p;  p += NX;
    u16* Hid = p; p += NX;
    (void)Xk; (void)Xv; (void)Wkb; (void)Wvb;

    cvt_all<<<8192, 256, 0, stream>>>(queries, keys, values, Wq, Wk, Wv, Wo, Xq);

    gemm_qkv<<<192, 512, 0, stream>>>(Xq, Wqb, bq, bk, bv, Qp, Kp, Vt);

    attn_kernel<<<256, 512, 0, stream>>>(Qp, Kp, Vt, Hid);

    gemm_out<<<512, 256, 0, stream>>>(Hid, Wob, bo, out);
}